// Round 1
// baseline (238.962 us; speedup 1.0000x reference)
//
#include <hip/hip_runtime.h>
#include <math.h>

#define NROW  131072
#define DIMC  64
#define KCODE 512
#define BM    64
#define KC    128

__global__ void e2_kernel(const float* __restrict__ e, float* __restrict__ e2,
                          double* __restrict__ dacc) {
  int k = blockIdx.x * 256 + threadIdx.x;
  if (k == 0) *dacc = 0.0;
  if (k < KCODE) {
    float s = 0.f;
    for (int d = 0; d < DIMC; ++d) {
      float v = e[d * KCODE + k];
      s = __fadd_rn(s, __fmul_rn(v, v));
    }
    e2[k] = s;
  }
}

__global__ void __launch_bounds__(256)
quant_kernel(const float* __restrict__ x, const float* __restrict__ e,
             const float* __restrict__ e2, float* __restrict__ out,
             float* __restrict__ oidx, double* __restrict__ dacc) {
  __shared__ float xsT[DIMC][BM + 4];
  __shared__ float es[DIMC][KC];
  __shared__ float e2s[KC];
  __shared__ float ss[BM];
  __shared__ int   ridx[BM];

  const int t = threadIdx.x;
  const long row0 = (long)blockIdx.x * BM;
  const float* xblk = x + row0 * DIMC;

  for (int w = 0; w < 4; ++w) {
    int f = t + w * 256;
    int row = f >> 4;
    int c0 = (f & 15) * 4;
    float4 v = *(const float4*)(xblk + f * 4);
    xsT[c0 + 0][row] = v.x;
    xsT[c0 + 1][row] = v.y;
    xsT[c0 + 2][row] = v.z;
    xsT[c0 + 3][row] = v.w;
  }
  __syncthreads();

  if (t < BM) {
    float s = 0.f;
    for (int d = 0; d < DIMC; ++d) {
      float v = xsT[d][t];
      s = __fadd_rn(s, __fmul_rn(v, v));
    }
    ss[t] = s;
  }

  const int tc = t & 15;
  const int tr = t >> 4;
  float minv[4];
  int   mini[4];
  for (int r = 0; r < 4; ++r) { minv[r] = INFINITY; mini[r] = 0; }

  for (int chunk = 0; chunk < 4; ++chunk) {
    __syncthreads();
    for (int w = 0; w < 8; ++w) {
      int f = t + w * 256;
      int d = f >> 5;
      int cv = (f & 31) * 4;
      float4 v = *(const float4*)(e + d * KCODE + chunk * KC + cv);
      *(float4*)&es[d][cv] = v;
    }
    if (t < KC / 4)
      *(float4*)&e2s[t * 4] = *(const float4*)(e2 + chunk * KC + t * 4);
    __syncthreads();

    float acc[4][8];
    for (int r = 0; r < 4; ++r)
      for (int j = 0; j < 8; ++j) acc[r][j] = 0.f;

    for (int d = 0; d < DIMC; ++d) {
      float a[4], b[8];
      *(float4*)&a[0] = *(const float4*)&xsT[d][tr * 4];
      *(float4*)&b[0] = *(const float4*)&es[d][tc * 8];
      *(float4*)&b[4] = *(const float4*)&es[d][tc * 8 + 4];
      for (int r = 0; r < 4; ++r)
        for (int j = 0; j < 8; ++j)
          acc[r][j] = fmaf(a[r], b[j], acc[r][j]);
    }

    for (int r = 0; r < 4; ++r) {
      float sr = ss[tr * 4 + r];
      for (int j = 0; j < 8; ++j) {
        int col = chunk * KC + tc * 8 + j;
        float dist = __fadd_rn(__fsub_rn(sr, __fmul_rn(2.0f, acc[r][j])), e2s[tc * 8 + j]);
        if (dist < minv[r]) { minv[r] = dist; mini[r] = col; }
      }
    }
  }

  for (int off = 1; off < 16; off <<= 1) {
    for (int r = 0; r < 4; ++r) {
      float ov = __shfl_xor(minv[r], off, 16);
      int   oi = __shfl_xor(mini[r], off, 16);
      if (ov < minv[r] || (ov == minv[r] && oi < mini[r])) {
        minv[r] = ov; mini[r] = oi;
      }
    }
  }
  if (tc == 0)
    for (int r = 0; r < 4; ++r) ridx[tr * 4 + r] = mini[r];
  __syncthreads();

  if (t < BM) oidx[row0 + t] = (float)ridx[t];

  double dsum = 0.0;
  for (int i = 0; i < 16; ++i) {
    int l = i * 256 + t;
    int row = l >> 6;
    int c = l & 63;
    int idx = ridx[row];
    float xv = xsT[c][row];
    float q = e[c * KCODE + idx];
    out[row0 * DIMC + l] = __fadd_rn(xv, __fsub_rn(q, xv));
    float dq = __fsub_rn(q, xv);
    dsum += (double)__fmul_rn(dq, dq);
  }
  for (int off = 32; off > 0; off >>= 1)
    dsum += __shfl_down(dsum, off, 64);
  if ((t & 63) == 0) atomicAdd(dacc, dsum);
}

__global__ void fin_kernel(const double* __restrict__ dacc,
                           float* __restrict__ diff_out,
                           float* __restrict__ perp_out) {
  double s = *dacc;
  *diff_out = (float)(s / 8388608.0);
  float p = 1.0f / 512.0f;
  float lp = logf(p + 1e-10f);
  *perp_out = expf(-(p * lp));
}

extern "C" void kernel_launch(void* const* d_in, const int* in_sizes, int n_in,
                              void* d_out, int out_size, void* d_ws, size_t ws_size,
                              hipStream_t stream) {
  const float* x = (const float*)d_in[0];
  const float* e = (const float*)d_in[1];
  float* out  = (float*)d_out;
  float* diff = out + 8388608;
  float* oidx = out + 8388609;
  float* perp = out + 8388609 + 131072;

  float*  e2   = (float*)d_ws;
  double* dacc = (double*)((char*)d_ws + 2048);

  e2_kernel<<<2, 256, 0, stream>>>(e, e2, dacc);
  quant_kernel<<<NROW / BM, 256, 0, stream>>>(x, e, e2, out, oidx, dacc);
  fin_kernel<<<1, 1, 0, stream>>>(dacc, diff, perp);
}